// Round 2
// baseline (412.405 us; speedup 1.0000x reference)
//
#include <hip/hip_runtime.h>
#include <hip/hip_bf16.h>

// Problem: B=8, T=256, V=32, D=256.
// Per-v GEMM: M=N=2048 (rows = i*T+q / j*T+k), K=256, then exp + 3 reductions.
// feature[B,T,V,D]: element (row, v, d) at feat[(row*32 + v)*256 + d].
// v3 structure (revert of v2's fp32-A fusion, keep the occupancy fix):
//  - repack converts BOTH tensors to fp8 e4m3 (A prescaled by log2 e), as in
//    the proven round-0 kernel.
//  - main: grid (16,32,2); blockIdx.z splits the 32-iter N-sweep in halves.
//    A fragments are loaded fp8 DIRECTLY from pA into registers (no As LDS):
//    16 x dwordx4 per lane, one-time, L1 absorbs the wave-pair duplicate.
//    LDS = 32 KB (B double buffer only) + __launch_bounds__(256,4)
//    -> 4 blocks/CU resident; desynced blocks overlap MFMA with exp.

typedef __attribute__((ext_vector_type(4))) float f32x4;
typedef __attribute__((ext_vector_type(4))) int   i32x4;
typedef __attribute__((ext_vector_type(8))) int   i32x8;
typedef __attribute__((ext_vector_type(8))) __bf16 bf16x8;   // fallback path

#if __has_builtin(__builtin_amdgcn_exp2f)
#define EXP2(x) __builtin_amdgcn_exp2f(x)
#else
#define EXP2(x) exp2f(x)
#endif

__device__ __forceinline__ unsigned short f2bf(float f) {
    unsigned u = __builtin_bit_cast(unsigned, f);
    u += 0x7FFFu + ((u >> 16) & 1u);   // RNE (no NaNs in data)
    return (unsigned short)(u >> 16);
}

template <bool HI>
__device__ __forceinline__ unsigned cvt2fp8(float a, float b, unsigned old) {
    return __builtin_amdgcn_cvt_pk_fp8_f32(a, b, old, HI);
}
__device__ __forceinline__ unsigned pack4fp8(float x, float y, float z, float w) {
    return cvt2fp8<true>(z, w, cvt2fp8<false>(x, y, 0u));
}

__device__ __forceinline__ void async16(const void* g, void* l) {
    __builtin_amdgcn_global_load_lds(
        (const __attribute__((address_space(1))) unsigned int*)g,
        (__attribute__((address_space(3))) unsigned int*)l,
        16, 0, 0);
}

__device__ __forceinline__ i32x8 cat8(i32x4 lo, i32x4 hi) {
    i32x8 r;
    r[0] = lo[0]; r[1] = lo[1]; r[2] = lo[2]; r[3] = lo[3];
    r[4] = hi[0]; r[5] = hi[1]; r[6] = hi[2]; r[7] = hi[3];
    return r;
}

// DPP row-sum over 16-lane rows; full sum lands in lane 15 of each row.
template <int CTRL>
__device__ __forceinline__ float dpp_add(float x) {
    int y = __builtin_amdgcn_update_dpp(0, __builtin_bit_cast(int, x),
                                        CTRL, 0xf, 0xf, true);
    return x + __builtin_bit_cast(float, y);
}
__device__ __forceinline__ float rowsum16(float x) {
    x = dpp_add<0x111>(x);   // row_shr:1
    x = dpp_add<0x112>(x);   // row_shr:2
    x = dpp_add<0x114>(x);   // row_shr:4
    x = dpp_add<0x118>(x);   // row_shr:8
    return x;
}

// ------------- repack: streaming fp32 -> fp8 e4m3 (plain layout) -------------
// grid (2048, 2): one row (8192 floats -> 8192 bytes) per block; y = tensor.
// Block (0,0) also zeroes the 3*2048 counter floats (replaces memset dispatch).
__global__ __launch_bounds__(256) void infonce_repack_fp8(
    const float* __restrict__ feat, const float* __restrict__ feat_aug,
    unsigned char* __restrict__ pA, unsigned char* __restrict__ pB,
    float* __restrict__ counters)
{
    const int row = blockIdx.x;
    const int tid = threadIdx.x;
    if (blockIdx.x == 0 && blockIdx.y == 0) {
        #pragma unroll
        for (int k = 0; k < 24; ++k) counters[k * 256 + tid] = 0.f;
    }
    const bool isA = (blockIdx.y == 0);
    const float sc = isA ? 1.4426950408889634f : 1.0f;
    const float* src = (isA ? feat : feat_aug) + (size_t)row * 8192;
    unsigned char* dst = (isA ? pA : pB) + (size_t)row * 8192;
    #pragma unroll
    for (int it = 0; it < 2; ++it) {
        const int base = it * 4096 + tid * 16;
        const float4 f0 = *(const float4*)(src + base);
        const float4 f1 = *(const float4*)(src + base + 4);
        const float4 f2 = *(const float4*)(src + base + 8);
        const float4 f3 = *(const float4*)(src + base + 12);
        uint4 p;
        p.x = pack4fp8(f0.x*sc, f0.y*sc, f0.z*sc, f0.w*sc);
        p.y = pack4fp8(f1.x*sc, f1.y*sc, f1.z*sc, f1.w*sc);
        p.z = pack4fp8(f2.x*sc, f2.y*sc, f2.z*sc, f2.w*sc);
        p.w = pack4fp8(f3.x*sc, f3.y*sc, f3.z*sc, f3.w*sc);
        *(uint4*)(dst + base) = p;
    }
}

// ----- main: half-N-sweep MX-fp8 GEMM + exp + reductions --------------------
// block = (tileM 0..15, v 0..31, zh 0..1). A frags fp8 direct from global.
// B: 2 x [64 rows][256 B] LDS double buffer, XOR-swizzled groups. 32 KB LDS.
__global__ __launch_bounds__(256, 4) void infonce_main_nl(
    const unsigned char* __restrict__ pA, const unsigned char* __restrict__ pB,
    float* __restrict__ total, float* __restrict__ selfp, float* __restrict__ ap)
{
    __shared__ __align__(16) unsigned char Bs[2][64 * 256];
    // scratch aliases Bs[0] after the final loop barrier
    float (*ls_row2)[128]  = (float (*)[128])(void*)&Bs[0][0];
    float (*ls_self2)[128] = (float (*)[128])(void*)&Bs[0][1024];

    const int tid  = threadIdx.x;
    const int lane = tid & 63;
    const int w    = tid >> 6;        // wave 0..3
    const int wm   = w >> 1;          // A rows half
    const int wn   = w & 1;           // B cols half (within 64-col tile)
    const int lrow = lane & 15;
    const int quad = lane >> 4;

    const int tileM = blockIdx.x;     // 0..15
    const int v     = blockIdx.y;     // 0..31
    const int zh    = blockIdx.z;     // 0..1: which half of the N-sweep
    const int n0    = zh * 16;
    const int n1    = n0 + 16;
    const int nD0   = (tileM >> 1) * 4;   // first diagonal n-iter (band of 4,
                                          // always fully inside one z-half)
    const bool hasDiag = (nD0 >= n0) && (nD0 < n1);

    const size_t vOff = (size_t)v * 256;

    // ---- stage first B half-tile (async; in flight during A frag loads) ----
    const size_t rowNbase = (size_t)(w * 16 + quad) * 8192 + vOff;
    {
        const unsigned char* srcB = pB + rowNbase + (size_t)n0 * 64 * 8192;
        #pragma unroll
        for (int i = 0; i < 4; ++i) {
            const int lg = (lrow ^ ((i * 4 + quad) & 15)) << 4;
            async16(srcB + (size_t)i * 4 * 8192 + lg,
                    &Bs[0][(w * 16 + i * 4) * 256]);
        }
    }

    // ---- A fragments: fp8 direct from global to registers ----
    // lane (lrow,quad) frag af[h][t] = A row (tileM*128+wm*64+t*16+lrow),
    // elements [h*128+quad*32, +32) (fragment slicing verified in v2).
    i32x8 af[2][4];   // [k-half][m-tile]
    #pragma unroll
    for (int t = 0; t < 4; ++t) {
        const unsigned char* rowA = pA +
            (size_t)(tileM * 128 + wm * 64 + t * 16 + lrow) * 8192 + vOff;
        #pragma unroll
        for (int h = 0; h < 2; ++h) {
            const unsigned char* s = rowA + h * 128 + quad * 32;
            af[h][t] = cat8(*(const i32x4*)s, *(const i32x4*)(s + 16));
        }
    }

    float rowp[4][4];   // row partials, all n in [n0,n1)
    float selfr[4][4];  // row partials, diagonal n only
    #pragma unroll
    for (int t = 0; t < 4; ++t)
        #pragma unroll
        for (int r = 0; r < 4; ++r) { rowp[t][r] = 0.f; selfr[t][r] = 0.f; }

    __syncthreads();   // B0 staged (barrier drains vmcnt)

    for (int n = n0; n < n1; ++n) {
        const int b = (n - n0) & 1;
        if (n < n1 - 1) {   // prefetch next B half-tile
            const unsigned char* src = pB + rowNbase + (size_t)(n + 1) * 64 * 8192;
            #pragma unroll
            for (int i = 0; i < 4; ++i) {
                const int lg = (lrow ^ ((i * 4 + quad) & 15)) << 4;
                async16(src + (size_t)i * 4 * 8192 + lg,
                        &Bs[b ^ 1][(w * 16 + i * 4) * 256]);
            }
        }
        f32x4 acc[4][2];
        #pragma unroll
        for (int t = 0; t < 4; ++t)
            #pragma unroll
            for (int tj = 0; tj < 2; ++tj)
                acc[t][tj] = (f32x4){0.f, 0.f, 0.f, 0.f};
        #pragma unroll
        for (int h = 0; h < 2; ++h) {
            i32x8 bf[2];
            #pragma unroll
            for (int tj = 0; tj < 2; ++tj) {
                const int rB = (wn * 32 + tj * 16 + lrow) * 256;
                const int g0 = ((h * 8 + quad * 2) ^ lrow) * 16;
                bf[tj] = cat8(*(const i32x4*)&Bs[b][rB + g0],
                              *(const i32x4*)&Bs[b][rB + (g0 ^ 16)]);
            }
            #pragma unroll
            for (int ti = 0; ti < 4; ++ti)
                #pragma unroll
                for (int tj = 0; tj < 2; ++tj)
                    acc[ti][tj] = __builtin_amdgcn_mfma_scale_f32_16x16x128_f8f6f4(
                        af[h][ti], bf[tj], acc[ti][tj],
                        0, 0, 0, 127, 0, 127);   // fp8/fp8, unit E8M0 scales
        }
        // epilogue-accumulate: E = exp2(acc) (A prescaled by log2 e)
        const bool diagIter = (n >= nD0) && (n < nD0 + 4);
        float colp0 = 0.f, colp1 = 0.f;
        #pragma unroll
        for (int t = 0; t < 4; ++t)
            #pragma unroll
            for (int r = 0; r < 4; ++r) {
                float e0 = EXP2(acc[t][0][r]);
                float e1 = EXP2(acc[t][1][r]);
                rowp[t][r] += e0 + e1;
                if (diagIter) { selfr[t][r] += e0 + e1; colp0 += e0; colp1 += e1; }
            }
        if (diagIter) {   // col sums -> ap (wave-uniform branch, 4 of 16 iters)
            float q0 = colp0, q1 = colp1;
            q0 += __shfl_xor(q0, 16); q0 += __shfl_xor(q0, 32);
            q1 += __shfl_xor(q1, 16); q1 += __shfl_xor(q1, 32);
            if (lane < 16) {
                atomicAdd(&ap[n * 64 + wn * 32 + lane], q0);
                atomicAdd(&ap[n * 64 + wn * 32 + 16 + lane], q1);
            }
        }
        __syncthreads();   // B[b] reads done + prefetch drained
    }

    // ---- final row reductions: DPP over the 16 cols held per lane-row ----
    #pragma unroll
    for (int t = 0; t < 4; ++t)
        #pragma unroll
        for (int r = 0; r < 4; ++r) {
            float rs = rowsum16(rowp[t][r]);
            float ss = rowsum16(selfr[t][r]);
            if (lrow == 15) {
                const int idx = wm * 64 + t * 16 + quad * 4 + r;
                ls_row2[wn][idx]  = rs;
                ls_self2[wn][idx] = ss;
            }
        }
    __syncthreads();
    if (tid < 128) {
        atomicAdd(&total[tileM * 128 + tid], ls_row2[0][tid] + ls_row2[1][tid]);
    } else if (hasDiag) {
        const int t2 = tid - 128;
        atomicAdd(&selfp[tileM * 128 + t2], ls_self2[0][t2] + ls_self2[1][t2]);
    }
}

// ---------------- fallback main (round-1 kernel, fp32 staging) ---------------
__global__ __launch_bounds__(256) void infonce_main_slow(
    const float* __restrict__ feat, const float* __restrict__ feat_aug,
    float* __restrict__ total, float* __restrict__ selfp, float* __restrict__ ap)
{
    __shared__ __align__(16) unsigned short As[128][72];
    __shared__ __align__(16) unsigned short Bs[128][72];
    __shared__ float ls_row[128];
    __shared__ float ls_col[128];

    const int tid  = threadIdx.x;
    const int lane = tid & 63;
    const int w    = tid >> 6;
    const int wm   = w >> 1;
    const int wn   = w & 1;
    const int lrow = lane & 15;
    const int quad = lane >> 4;

    const int tileM = blockIdx.x & 15;
    const int tileN = blockIdx.x >> 4;
    const int v     = blockIdx.y;
    const bool diag = (tileM >> 1) == (tileN >> 1);

    if (tid < 128) ls_row[tid] = 0.0f;
    else           ls_col[tid - 128] = 0.0f;

    const float* aBase = feat     + (size_t)v * 256;
    const float* bBase = feat_aug + (size_t)v * 256;

    f32x4 acc[4][4];
    #pragma unroll
    for (int i = 0; i < 4; ++i)
        #pragma unroll
        for (int j = 0; j < 4; ++j)
            acc[i][j] = (f32x4){0.f, 0.f, 0.f, 0.f};

    const int srow = tid >> 4;
    const int scol = (tid & 15) * 4;

    for (int s = 0; s < 4; ++s) {
        const int k0 = s * 64;
        if (s) __syncthreads();
        #pragma unroll
        for (int it = 0; it < 8; ++it) {
            const int row = it * 16 + srow;
            const float4 a4 = *(const float4*)(aBase + (size_t)(tileM * 128 + row) * 8192 + k0 + scol);
            const float4 b4 = *(const float4*)(bBase + (size_t)(tileN * 128 + row) * 8192 + k0 + scol);
            uint2 wa, wb;
            wa.x = (unsigned)f2bf(a4.x) | ((unsigned)f2bf(a4.y) << 16);
            wa.y = (unsigned)f2bf(a4.z) | ((unsigned)f2bf(a4.w) << 16);
            wb.x = (unsigned)f2bf(b4.x) | ((unsigned)f2bf(b4.y) << 16);
            wb.y = (unsigned)f2bf(b4.z) | ((unsigned)f2bf(b4.w) << 16);
            *(uint2*)&As[row][scol] = wa;
            *(uint2*)&Bs[row][scol] = wb;
        }
        __syncthreads();
        #pragma unroll
        for (int kk = 0; kk < 64; kk += 32) {
            bf16x8 af[4], bfr[4];
            #pragma unroll
            for (int t = 0; t < 4; ++t) {
                af[t]  = *(const bf16x8*)&As[wm * 64 + t * 16 + lrow][kk + quad * 8];
                bfr[t] = *(const bf16x8*)&Bs[wn * 64 + t * 16 + lrow][kk + quad * 8];
            }
            #pragma unroll
            for (int ti = 0; ti < 4; ++ti)
                #pragma unroll
                for (int tj = 0; tj < 4; ++tj)
                    acc[ti][tj] = __builtin_amdgcn_mfma_f32_16x16x32_bf16(
                        af[ti], bfr[tj], acc[ti][tj], 0, 0, 0);
        }
    }

    float colp[4] = {0.f, 0.f, 0.f, 0.f};
    #pragma unroll
    for (int ti = 0; ti < 4; ++ti) {
        #pragma unroll
        for (int r = 0; r < 4; ++r) {
            float e0 = __expf(acc[ti][0][r]);
            float e1 = __expf(acc[ti][1][r]);
            float e2 = __expf(acc[ti][2][r]);
            float e3 = __expf(acc[ti][3][r]);
            colp[0] += e0; colp[1] += e1; colp[2] += e2; colp[3] += e3;
            float rp = (e0 + e1) + (e2 + e3);
            rp += __shfl_xor(rp, 1);
            rp += __shfl_xor(rp, 2);
            rp += __shfl_xor(rp, 4);
            rp += __shfl_xor(rp, 8);
            if (lrow == 0)
                atomicAdd(&ls_row[wm * 64 + ti * 16 + quad * 4 + r], rp);
        }
    }
    if (diag) {
        #pragma unroll
        for (int tj = 0; tj < 4; ++tj) {
            float q = colp[tj];
            q += __shfl_xor(q, 16);
            q += __shfl_xor(q, 32);
            if (lane < 16)
                atomicAdd(&ls_col[wn * 64 + tj * 16 + lane], q);
        }
    }
    __syncthreads();
    if (tid < 128) {
        const float rs = ls_row[tid];
        const int rowg = tileM * 128 + tid;
        atomicAdd(&total[rowg], rs);
        if (diag) atomicAdd(&selfp[rowg], rs);
    } else if (diag) {
        const int t2 = tid - 128;
        atomicAdd(&ap[tileN * 128 + t2], ls_col[t2]);
    }
}

__global__ __launch_bounds__(256) void infonce_finalize(
    const float* __restrict__ total, const float* __restrict__ selfp,
    const float* __restrict__ ap, float* __restrict__ out)
{
    __shared__ float red[4];
    const int tid = threadIdx.x;
    float s = 0.f;
    for (int e = tid; e < 2048; e += 256) {
        const float an = total[e] - selfp[e];
        s += logf(an / ap[e]);
    }
    #pragma unroll
    for (int m = 32; m >= 1; m >>= 1) s += __shfl_xor(s, m);
    if ((tid & 63) == 0) red[tid >> 6] = s;
    __syncthreads();
    if (tid == 0) out[0] = (red[0] + red[1] + red[2] + red[3]) * (1.0f / 256.0f);
}

extern "C" void kernel_launch(void* const* d_in, const int* in_sizes, int n_in,
                              void* d_out, int out_size, void* d_ws, size_t ws_size,
                              hipStream_t stream) {
    const float* feat     = (const float*)d_in[0];
    const float* feat_aug = (const float*)d_in[1];
    float* total = (float*)d_ws;
    float* selfp = total + 2048;
    float* ap    = selfp + 2048;

    const size_t packBytes = (size_t)2048 * 8192;                  // per tensor, fp8
    const size_t need = 32768 + 2 * packBytes;
    if (ws_size >= need) {
        unsigned char* pA = (unsigned char*)d_ws + 32768;
        unsigned char* pB = pA + packBytes;
        infonce_repack_fp8<<<dim3(2048, 2), 256, 0, stream>>>(feat, feat_aug, pA, pB, total);
        infonce_main_nl<<<dim3(16, 32, 2), 256, 0, stream>>>(pA, pB, total, selfp, ap);
    } else {
        (void)hipMemsetAsync(d_ws, 0, 3 * 2048 * sizeof(float), stream);
        infonce_main_slow<<<dim3(256, 32), 256, 0, stream>>>(feat, feat_aug, total, selfp, ap);
    }
    infonce_finalize<<<1, 256, 0, stream>>>(total, selfp, ap, (float*)d_out);
}

// Round 3
// 205.897 us; speedup vs baseline: 2.0030x; 2.0030x over previous
//
#include <hip/hip_runtime.h>
#include <hip/hip_bf16.h>

// Problem: B=8, T=256, V=32, D=256.
// Per-v GEMM: M=N=2048 (rows = i*T+q / j*T+k), K=256, then exp + 3 reductions.
// feature[B,T,V,D]: element (row, v, d) at feat[(row*32 + v)*256 + d].
// v4 = v3 with the register budget fixed:
//  - repack converts BOTH tensors to fp8 e4m3 (A prescaled by log2 e).
//  - main: grid (16,32,2); blockIdx.z splits the 32-iter N-sweep in halves.
//    A fragments loaded fp8 DIRECTLY from pA into registers (no As LDS).
//    LDS = 32 KB (B double buffer only).
//  - __launch_bounds__(256, 3): cap 170 VGPR (v3's (256,4) forced 64 VGPR ->
//    358 MB of spill scratch writes, 5x regression). 3-4 blocks/CU resident,
//    no spill; desynced blocks overlap MFMA with neighbors' exp epilogue.

typedef __attribute__((ext_vector_type(4))) float f32x4;
typedef __attribute__((ext_vector_type(4))) int   i32x4;
typedef __attribute__((ext_vector_type(8))) int   i32x8;
typedef __attribute__((ext_vector_type(8))) __bf16 bf16x8;   // fallback path

#if __has_builtin(__builtin_amdgcn_exp2f)
#define EXP2(x) __builtin_amdgcn_exp2f(x)
#else
#define EXP2(x) exp2f(x)
#endif

__device__ __forceinline__ unsigned short f2bf(float f) {
    unsigned u = __builtin_bit_cast(unsigned, f);
    u += 0x7FFFu + ((u >> 16) & 1u);   // RNE (no NaNs in data)
    return (unsigned short)(u >> 16);
}

template <bool HI>
__device__ __forceinline__ unsigned cvt2fp8(float a, float b, unsigned old) {
    return __builtin_amdgcn_cvt_pk_fp8_f32(a, b, old, HI);
}
__device__ __forceinline__ unsigned pack4fp8(float x, float y, float z, float w) {
    return cvt2fp8<true>(z, w, cvt2fp8<false>(x, y, 0u));
}

__device__ __forceinline__ void async16(const void* g, void* l) {
    __builtin_amdgcn_global_load_lds(
        (const __attribute__((address_space(1))) unsigned int*)g,
        (__attribute__((address_space(3))) unsigned int*)l,
        16, 0, 0);
}

__device__ __forceinline__ i32x8 cat8(i32x4 lo, i32x4 hi) {
    i32x8 r;
    r[0] = lo[0]; r[1] = lo[1]; r[2] = lo[2]; r[3] = lo[3];
    r[4] = hi[0]; r[5] = hi[1]; r[6] = hi[2]; r[7] = hi[3];
    return r;
}

// DPP row-sum over 16-lane rows; full sum lands in lane 15 of each row.
template <int CTRL>
__device__ __forceinline__ float dpp_add(float x) {
    int y = __builtin_amdgcn_update_dpp(0, __builtin_bit_cast(int, x),
                                        CTRL, 0xf, 0xf, true);
    return x + __builtin_bit_cast(float, y);
}
__device__ __forceinline__ float rowsum16(float x) {
    x = dpp_add<0x111>(x);   // row_shr:1
    x = dpp_add<0x112>(x);   // row_shr:2
    x = dpp_add<0x114>(x);   // row_shr:4
    x = dpp_add<0x118>(x);   // row_shr:8
    return x;
}

// ------------- repack: streaming fp32 -> fp8 e4m3 (plain layout) -------------
// grid (2048, 2): one row (8192 floats -> 8192 bytes) per block; y = tensor.
// Block (0,0) also zeroes the 3*2048 counter floats (replaces memset dispatch).
__global__ __launch_bounds__(256) void infonce_repack_fp8(
    const float* __restrict__ feat, const float* __restrict__ feat_aug,
    unsigned char* __restrict__ pA, unsigned char* __restrict__ pB,
    float* __restrict__ counters)
{
    const int row = blockIdx.x;
    const int tid = threadIdx.x;
    if (blockIdx.x == 0 && blockIdx.y == 0) {
        #pragma unroll
        for (int k = 0; k < 24; ++k) counters[k * 256 + tid] = 0.f;
    }
    const bool isA = (blockIdx.y == 0);
    const float sc = isA ? 1.4426950408889634f : 1.0f;
    const float* src = (isA ? feat : feat_aug) + (size_t)row * 8192;
    unsigned char* dst = (isA ? pA : pB) + (size_t)row * 8192;
    #pragma unroll
    for (int it = 0; it < 2; ++it) {
        const int base = it * 4096 + tid * 16;
        const float4 f0 = *(const float4*)(src + base);
        const float4 f1 = *(const float4*)(src + base + 4);
        const float4 f2 = *(const float4*)(src + base + 8);
        const float4 f3 = *(const float4*)(src + base + 12);
        uint4 p;
        p.x = pack4fp8(f0.x*sc, f0.y*sc, f0.z*sc, f0.w*sc);
        p.y = pack4fp8(f1.x*sc, f1.y*sc, f1.z*sc, f1.w*sc);
        p.z = pack4fp8(f2.x*sc, f2.y*sc, f2.z*sc, f2.w*sc);
        p.w = pack4fp8(f3.x*sc, f3.y*sc, f3.z*sc, f3.w*sc);
        *(uint4*)(dst + base) = p;
    }
}

// ----- main: half-N-sweep MX-fp8 GEMM + exp + reductions --------------------
// block = (tileM 0..15, v 0..31, zh 0..1). A frags fp8 direct from global.
// B: 2 x [64 rows][256 B] LDS double buffer, XOR-swizzled groups. 32 KB LDS.
__global__ __launch_bounds__(256, 3) void infonce_main_nl(
    const unsigned char* __restrict__ pA, const unsigned char* __restrict__ pB,
    float* __restrict__ total, float* __restrict__ selfp, float* __restrict__ ap)
{
    __shared__ __align__(16) unsigned char Bs[2][64 * 256];
    // scratch aliases Bs[0] after the final loop barrier
    float (*ls_row2)[128]  = (float (*)[128])(void*)&Bs[0][0];
    float (*ls_self2)[128] = (float (*)[128])(void*)&Bs[0][1024];

    const int tid  = threadIdx.x;
    const int lane = tid & 63;
    const int w    = tid >> 6;        // wave 0..3
    const int wm   = w >> 1;          // A rows half
    const int wn   = w & 1;           // B cols half (within 64-col tile)
    const int lrow = lane & 15;
    const int quad = lane >> 4;

    const int tileM = blockIdx.x;     // 0..15
    const int v     = blockIdx.y;     // 0..31
    const int zh    = blockIdx.z;     // 0..1: which half of the N-sweep
    const int n0    = zh * 16;
    const int n1    = n0 + 16;
    const int nD0   = (tileM >> 1) * 4;   // first diagonal n-iter (band of 4,
                                          // always fully inside one z-half)
    const bool hasDiag = (nD0 >= n0) && (nD0 < n1);

    const size_t vOff = (size_t)v * 256;

    // ---- stage first B half-tile (async; in flight during A frag loads) ----
    const size_t rowNbase = (size_t)(w * 16 + quad) * 8192 + vOff;
    {
        const unsigned char* srcB = pB + rowNbase + (size_t)n0 * 64 * 8192;
        #pragma unroll
        for (int i = 0; i < 4; ++i) {
            const int lg = (lrow ^ ((i * 4 + quad) & 15)) << 4;
            async16(srcB + (size_t)i * 4 * 8192 + lg,
                    &Bs[0][(w * 16 + i * 4) * 256]);
        }
    }

    // ---- A fragments: fp8 direct from global to registers ----
    // lane (lrow,quad) frag af[h][t] = A row (tileM*128+wm*64+t*16+lrow),
    // elements [h*128+quad*32, +32) (fragment slicing verified in v2).
    i32x8 af[2][4];   // [k-half][m-tile]
    #pragma unroll
    for (int t = 0; t < 4; ++t) {
        const unsigned char* rowA = pA +
            (size_t)(tileM * 128 + wm * 64 + t * 16 + lrow) * 8192 + vOff;
        #pragma unroll
        for (int h = 0; h < 2; ++h) {
            const unsigned char* s = rowA + h * 128 + quad * 32;
            af[h][t] = cat8(*(const i32x4*)s, *(const i32x4*)(s + 16));
        }
    }

    float rowp[4][4];   // row partials, all n in [n0,n1)
    float selfr[4][4];  // row partials, diagonal n only
    #pragma unroll
    for (int t = 0; t < 4; ++t)
        #pragma unroll
        for (int r = 0; r < 4; ++r) { rowp[t][r] = 0.f; selfr[t][r] = 0.f; }

    __syncthreads();   // B0 staged (barrier drains vmcnt)

    for (int n = n0; n < n1; ++n) {
        const int b = (n - n0) & 1;
        if (n < n1 - 1) {   // prefetch next B half-tile
            const unsigned char* src = pB + rowNbase + (size_t)(n + 1) * 64 * 8192;
            #pragma unroll
            for (int i = 0; i < 4; ++i) {
                const int lg = (lrow ^ ((i * 4 + quad) & 15)) << 4;
                async16(src + (size_t)i * 4 * 8192 + lg,
                        &Bs[b ^ 1][(w * 16 + i * 4) * 256]);
            }
        }
        f32x4 acc[4][2];
        #pragma unroll
        for (int t = 0; t < 4; ++t)
            #pragma unroll
            for (int tj = 0; tj < 2; ++tj)
                acc[t][tj] = (f32x4){0.f, 0.f, 0.f, 0.f};
        #pragma unroll
        for (int h = 0; h < 2; ++h) {
            i32x8 bf[2];
            #pragma unroll
            for (int tj = 0; tj < 2; ++tj) {
                const int rB = (wn * 32 + tj * 16 + lrow) * 256;
                const int g0 = ((h * 8 + quad * 2) ^ lrow) * 16;
                bf[tj] = cat8(*(const i32x4*)&Bs[b][rB + g0],
                              *(const i32x4*)&Bs[b][rB + (g0 ^ 16)]);
            }
            #pragma unroll
            for (int ti = 0; ti < 4; ++ti)
                #pragma unroll
                for (int tj = 0; tj < 2; ++tj)
                    acc[ti][tj] = __builtin_amdgcn_mfma_scale_f32_16x16x128_f8f6f4(
                        af[h][ti], bf[tj], acc[ti][tj],
                        0, 0, 0, 127, 0, 127);   // fp8/fp8, unit E8M0 scales
        }
        // epilogue-accumulate: E = exp2(acc) (A prescaled by log2 e)
        const bool diagIter = (n >= nD0) && (n < nD0 + 4);
        float colp0 = 0.f, colp1 = 0.f;
        #pragma unroll
        for (int t = 0; t < 4; ++t)
            #pragma unroll
            for (int r = 0; r < 4; ++r) {
                float e0 = EXP2(acc[t][0][r]);
                float e1 = EXP2(acc[t][1][r]);
                rowp[t][r] += e0 + e1;
                if (diagIter) { selfr[t][r] += e0 + e1; colp0 += e0; colp1 += e1; }
            }
        if (diagIter) {   // col sums -> ap (wave-uniform branch, 4 of 16 iters)
            float q0 = colp0, q1 = colp1;
            q0 += __shfl_xor(q0, 16); q0 += __shfl_xor(q0, 32);
            q1 += __shfl_xor(q1, 16); q1 += __shfl_xor(q1, 32);
            if (lane < 16) {
                atomicAdd(&ap[n * 64 + wn * 32 + lane], q0);
                atomicAdd(&ap[n * 64 + wn * 32 + 16 + lane], q1);
            }
        }
        __syncthreads();   // B[b] reads done + prefetch drained
    }

    // ---- final row reductions: DPP over the 16 cols held per lane-row ----
    #pragma unroll
    for (int t = 0; t < 4; ++t)
        #pragma unroll
        for (int r = 0; r < 4; ++r) {
            float rs = rowsum16(rowp[t][r]);
            float ss = rowsum16(selfr[t][r]);
            if (lrow == 15) {
                const int idx = wm * 64 + t * 16 + quad * 4 + r;
                ls_row2[wn][idx]  = rs;
                ls_self2[wn][idx] = ss;
            }
        }
    __syncthreads();
    if (tid < 128) {
        atomicAdd(&total[tileM * 128 + tid], ls_row2[0][tid] + ls_row2[1][tid]);
    } else if (hasDiag) {
        const int t2 = tid - 128;
        atomicAdd(&selfp[tileM * 128 + t2], ls_self2[0][t2] + ls_self2[1][t2]);
    }
}

// ---------------- fallback main (round-1 kernel, fp32 staging) ---------------
__global__ __launch_bounds__(256) void infonce_main_slow(
    const float* __restrict__ feat, const float* __restrict__ feat_aug,
    float* __restrict__ total, float* __restrict__ selfp, float* __restrict__ ap)
{
    __shared__ __align__(16) unsigned short As[128][72];
    __shared__ __align__(16) unsigned short Bs[128][72];
    __shared__ float ls_row[128];
    __shared__ float ls_col[128];

    const int tid  = threadIdx.x;
    const int lane = tid & 63;
    const int w    = tid >> 6;
    const int wm   = w >> 1;
    const int wn   = w & 1;
    const int lrow = lane & 15;
    const int quad = lane >> 4;

    const int tileM = blockIdx.x & 15;
    const int tileN = blockIdx.x >> 4;
    const int v     = blockIdx.y;
    const bool diag = (tileM >> 1) == (tileN >> 1);

    if (tid < 128) ls_row[tid] = 0.0f;
    else           ls_col[tid - 128] = 0.0f;

    const float* aBase = feat     + (size_t)v * 256;
    const float* bBase = feat_aug + (size_t)v * 256;

    f32x4 acc[4][4];
    #pragma unroll
    for (int i = 0; i < 4; ++i)
        #pragma unroll
        for (int j = 0; j < 4; ++j)
            acc[i][j] = (f32x4){0.f, 0.f, 0.f, 0.f};

    const int srow = tid >> 4;
    const int scol = (tid & 15) * 4;

    for (int s = 0; s < 4; ++s) {
        const int k0 = s * 64;
        if (s) __syncthreads();
        #pragma unroll
        for (int it = 0; it < 8; ++it) {
            const int row = it * 16 + srow;
            const float4 a4 = *(const float4*)(aBase + (size_t)(tileM * 128 + row) * 8192 + k0 + scol);
            const float4 b4 = *(const float4*)(bBase + (size_t)(tileN * 128 + row) * 8192 + k0 + scol);
            uint2 wa, wb;
            wa.x = (unsigned)f2bf(a4.x) | ((unsigned)f2bf(a4.y) << 16);
            wa.y = (unsigned)f2bf(a4.z) | ((unsigned)f2bf(a4.w) << 16);
            wb.x = (unsigned)f2bf(b4.x) | ((unsigned)f2bf(b4.y) << 16);
            wb.y = (unsigned)f2bf(b4.z) | ((unsigned)f2bf(b4.w) << 16);
            *(uint2*)&As[row][scol] = wa;
            *(uint2*)&Bs[row][scol] = wb;
        }
        __syncthreads();
        #pragma unroll
        for (int kk = 0; kk < 64; kk += 32) {
            bf16x8 af[4], bfr[4];
            #pragma unroll
            for (int t = 0; t < 4; ++t) {
                af[t]  = *(const bf16x8*)&As[wm * 64 + t * 16 + lrow][kk + quad * 8];
                bfr[t] = *(const bf16x8*)&Bs[wn * 64 + t * 16 + lrow][kk + quad * 8];
            }
            #pragma unroll
            for (int ti = 0; ti < 4; ++ti)
                #pragma unroll
                for (int tj = 0; tj < 4; ++tj)
                    acc[ti][tj] = __builtin_amdgcn_mfma_f32_16x16x32_bf16(
                        af[ti], bfr[tj], acc[ti][tj], 0, 0, 0);
        }
    }

    float colp[4] = {0.f, 0.f, 0.f, 0.f};
    #pragma unroll
    for (int ti = 0; ti < 4; ++ti) {
        #pragma unroll
        for (int r = 0; r < 4; ++r) {
            float e0 = __expf(acc[ti][0][r]);
            float e1 = __expf(acc[ti][1][r]);
            float e2 = __expf(acc[ti][2][r]);
            float e3 = __expf(acc[ti][3][r]);
            colp[0] += e0; colp[1] += e1; colp[2] += e2; colp[3] += e3;
            float rp = (e0 + e1) + (e2 + e3);
            rp += __shfl_xor(rp, 1);
            rp += __shfl_xor(rp, 2);
            rp += __shfl_xor(rp, 4);
            rp += __shfl_xor(rp, 8);
            if (lrow == 0)
                atomicAdd(&ls_row[wm * 64 + ti * 16 + quad * 4 + r], rp);
        }
    }
    if (diag) {
        #pragma unroll
        for (int tj = 0; tj < 4; ++tj) {
            float q = colp[tj];
            q += __shfl_xor(q, 16);
            q += __shfl_xor(q, 32);
            if (lane < 16)
                atomicAdd(&ls_col[wn * 64 + tj * 16 + lane], q);
        }
    }
    __syncthreads();
    if (tid < 128) {
        const float rs = ls_row[tid];
        const int rowg = tileM * 128 + tid;
        atomicAdd(&total[rowg], rs);
        if (diag) atomicAdd(&selfp[rowg], rs);
    } else if (diag) {
        const int t2 = tid - 128;
        atomicAdd(&ap[tileN * 128 + t2], ls_col[t2]);
    }
}

__global__ __launch_bounds__(256) void infonce_finalize(
    const float* __restrict__ total, const float* __restrict__ selfp,
    const float* __restrict__ ap, float* __restrict__ out)
{
    __shared__ float red[4];
    const int tid = threadIdx.x;
    float s = 0.f;
    for (int e = tid; e < 2048; e += 256) {
        const float an = total[e] - selfp[e];
        s += logf(an / ap[e]);
    }
    #pragma unroll
    for (int m = 32; m >= 1; m >>= 1) s += __shfl_xor(s, m);
    if ((tid & 63) == 0) red[tid >> 6] = s;
    __syncthreads();
    if (tid == 0) out[0] = (red[0] + red[1] + red[2] + red[3]) * (1.0f / 256.0f);
}

extern "C" void kernel_launch(void* const* d_in, const int* in_sizes, int n_in,
                              void* d_out, int out_size, void* d_ws, size_t ws_size,
                              hipStream_t stream) {
    const float* feat     = (const float*)d_in[0];
    const float* feat_aug = (const float*)d_in[1];
    float* total = (float*)d_ws;
    float* selfp = total + 2048;
    float* ap    = selfp + 2048;

    const size_t packBytes = (size_t)2048 * 8192;                  // per tensor, fp8
    const size_t need = 32768 + 2 * packBytes;
    if (ws_size >= need) {
        unsigned char* pA = (unsigned char*)d_ws + 32768;
        unsigned char* pB = pA + packBytes;
        infonce_repack_fp8<<<dim3(2048, 2), 256, 0, stream>>>(feat, feat_aug, pA, pB, total);
        infonce_main_nl<<<dim3(16, 32, 2), 256, 0, stream>>>(pA, pB, total, selfp, ap);
    } else {
        (void)hipMemsetAsync(d_ws, 0, 3 * 2048 * sizeof(float), stream);
        infonce_main_slow<<<dim3(256, 32), 256, 0, stream>>>(feat, feat_aug, total, selfp, ap);
    }
    infonce_finalize<<<1, 256, 0, stream>>>(total, selfp, ap, (float*)d_out);
}

// Round 5
// 185.302 us; speedup vs baseline: 2.2256x; 1.1111x over previous
//
#include <hip/hip_runtime.h>
#include <hip/hip_bf16.h>

// Problem: B=8, T=256, V=32, D=256.
// Per-v GEMM: M=N=2048 (rows = i*T+q / j*T+k), K=256, then exp + 3 reductions.
// feature[B,T,V,D]: element (row, v, d) at feat[(row*32 + v)*256 + d].
// v5b = v5 resubmit (round-4 bench died container-side, no counters).
// Round-0 structure (As 32KB + Bs 2x16KB LDS, grid (16,32), 2 blocks/CU)
// with the barrier-drain stall removed (T3/T4 counted vmcnt):
//  - old __syncthreads() per iter drained vmcnt(0), serializing every
//    iteration on the just-issued prefetch (~500-900 cyc x 32 iters).
//  - New loop: raw s_barrier + s_waitcnt vmcnt(4) (never 0 mid-loop); stage
//    tile n+2 right after all waves finish ds_reads of tile n -> each stage
//    has TWO full iterations of flight time. setprio(1) around MFMA (T5).
//  - sched_barrier(0) after each inline-asm wait (rule #18).
//  - last iteration peeled: hot loop is branch-free around the asm waits.

typedef __attribute__((ext_vector_type(4))) float f32x4;
typedef __attribute__((ext_vector_type(4))) int   i32x4;
typedef __attribute__((ext_vector_type(8))) int   i32x8;
typedef __attribute__((ext_vector_type(8))) __bf16 bf16x8;   // fallback path

#if __has_builtin(__builtin_amdgcn_exp2f)
#define EXP2(x) __builtin_amdgcn_exp2f(x)
#else
#define EXP2(x) exp2f(x)
#endif

#define WAIT_VMCNT(N)                                              \
    do {                                                           \
        asm volatile("s_waitcnt vmcnt(" #N ")" ::: "memory");      \
        __builtin_amdgcn_sched_barrier(0);                         \
    } while (0)
#define WAIT_LGKM0                                                 \
    do {                                                           \
        asm volatile("s_waitcnt lgkmcnt(0)" ::: "memory");         \
        __builtin_amdgcn_sched_barrier(0);                         \
    } while (0)
#define BARRIER()                                                  \
    do {                                                           \
        __builtin_amdgcn_s_barrier();                              \
        __builtin_amdgcn_sched_barrier(0);                         \
    } while (0)

__device__ __forceinline__ unsigned short f2bf(float f) {
    unsigned u = __builtin_bit_cast(unsigned, f);
    u += 0x7FFFu + ((u >> 16) & 1u);   // RNE (no NaNs in data)
    return (unsigned short)(u >> 16);
}

template <bool HI>
__device__ __forceinline__ unsigned cvt2fp8(float a, float b, unsigned old) {
    return __builtin_amdgcn_cvt_pk_fp8_f32(a, b, old, HI);
}
__device__ __forceinline__ unsigned pack4fp8(float x, float y, float z, float w) {
    return cvt2fp8<true>(z, w, cvt2fp8<false>(x, y, 0u));
}

__device__ __forceinline__ void async16(const void* g, void* l) {
    __builtin_amdgcn_global_load_lds(
        (const __attribute__((address_space(1))) unsigned int*)g,
        (__attribute__((address_space(3))) unsigned int*)l,
        16, 0, 0);
}

__device__ __forceinline__ i32x8 cat8(i32x4 lo, i32x4 hi) {
    i32x8 r;
    r[0] = lo[0]; r[1] = lo[1]; r[2] = lo[2]; r[3] = lo[3];
    r[4] = hi[0]; r[5] = hi[1]; r[6] = hi[2]; r[7] = hi[3];
    return r;
}

// DPP row-sum over 16-lane rows; full sum lands in lane 15 of each row.
template <int CTRL>
__device__ __forceinline__ float dpp_add(float x) {
    int y = __builtin_amdgcn_update_dpp(0, __builtin_bit_cast(int, x),
                                        CTRL, 0xf, 0xf, true);
    return x + __builtin_bit_cast(float, y);
}
__device__ __forceinline__ float rowsum16(float x) {
    x = dpp_add<0x111>(x);   // row_shr:1
    x = dpp_add<0x112>(x);   // row_shr:2
    x = dpp_add<0x114>(x);   // row_shr:4
    x = dpp_add<0x118>(x);   // row_shr:8
    return x;
}

// ------------- repack: streaming fp32 -> fp8 e4m3 (plain layout) -------------
// grid (2048, 2): one row (8192 floats -> 8192 bytes) per block; y = tensor.
// Block (0,0) also zeroes the 3*2048 counter floats (replaces memset dispatch).
__global__ __launch_bounds__(256) void infonce_repack_fp8(
    const float* __restrict__ feat, const float* __restrict__ feat_aug,
    unsigned char* __restrict__ pA, unsigned char* __restrict__ pB,
    float* __restrict__ counters)
{
    const int row = blockIdx.x;
    const int tid = threadIdx.x;
    if (blockIdx.x == 0 && blockIdx.y == 0) {
        #pragma unroll
        for (int k = 0; k < 24; ++k) counters[k * 256 + tid] = 0.f;
    }
    const bool isA = (blockIdx.y == 0);
    const float sc = isA ? 1.4426950408889634f : 1.0f;
    const float* src = (isA ? feat : feat_aug) + (size_t)row * 8192;
    unsigned char* dst = (isA ? pA : pB) + (size_t)row * 8192;
    #pragma unroll
    for (int it = 0; it < 2; ++it) {
        const int base = it * 4096 + tid * 16;
        const float4 f0 = *(const float4*)(src + base);
        const float4 f1 = *(const float4*)(src + base + 4);
        const float4 f2 = *(const float4*)(src + base + 8);
        const float4 f3 = *(const float4*)(src + base + 12);
        uint4 p;
        p.x = pack4fp8(f0.x*sc, f0.y*sc, f0.z*sc, f0.w*sc);
        p.y = pack4fp8(f1.x*sc, f1.y*sc, f1.z*sc, f1.w*sc);
        p.z = pack4fp8(f2.x*sc, f2.y*sc, f2.z*sc, f2.w*sc);
        p.w = pack4fp8(f3.x*sc, f3.y*sc, f3.z*sc, f3.w*sc);
        *(uint4*)(dst + base) = p;
    }
}

// ----- main: N-sweep MX-fp8 GEMM + exp + reductions, counted-vmcnt pipeline --
// block = (tileM 0..15, v 0..31). A: [128 rows][16 groups x 16B] in LDS once,
// frags hoisted to regs. B: 2 x [64 rows][256 B] double buffer. 64 KB LDS.
__global__ __launch_bounds__(256, 2) void infonce_main_nl(
    const unsigned char* __restrict__ pA, const unsigned char* __restrict__ pB,
    float* __restrict__ total, float* __restrict__ selfp, float* __restrict__ ap)
{
    __shared__ __align__(16) unsigned char As[128 * 256];
    __shared__ __align__(16) unsigned char Bs[2][64 * 256];
    // scratch aliases As after the final loop barrier (A frags live in regs)
    float (*ls_row2)[128]  = (float (*)[128])(void*)As;
    float (*ls_self2)[128] = (float (*)[128])(void*)(As + 1024);

    const int tid  = threadIdx.x;
    const int lane = tid & 63;
    const int w    = tid >> 6;        // wave 0..3
    const int wm   = w >> 1;          // A rows half
    const int wn   = w & 1;           // B cols half (within 64-col tile)
    const int lrow = lane & 15;
    const int quad = lane >> 4;

    const int tileM = blockIdx.x;     // 0..15
    const int v     = blockIdx.y;     // 0..31
    const int nD0   = (tileM >> 1) * 4;   // first diagonal n-iter

    const size_t vOff = (size_t)v * 256;

    // ---- stage A (128 rows x 256 B), swizzled, once ----
    {
        const size_t rowM = (size_t)(tileM * 128 + w * 32 + quad) * 8192 + vOff;
        #pragma unroll
        for (int i = 0; i < 8; ++i) {
            const int lg = (lrow ^ ((i * 4 + quad) & 15)) << 4;
            async16(pA + rowM + (size_t)i * 4 * 8192 + lg, &As[(w * 32 + i * 4) * 256]);
        }
    }
    // ---- stage B tiles 0 and 1 (pipeline depth 2) ----
    const size_t rowNbase = (size_t)(w * 16 + quad) * 8192 + vOff;
    #pragma unroll
    for (int nn = 0; nn < 2; ++nn) {
        const unsigned char* srcB = pB + rowNbase + (size_t)nn * 64 * 8192;
        #pragma unroll
        for (int i = 0; i < 4; ++i) {
            const int lg = (lrow ^ ((i * 4 + quad) & 15)) << 4;
            async16(srcB + (size_t)i * 4 * 8192 + lg,
                    &Bs[nn][(w * 16 + i * 4) * 256]);
        }
    }
    // A(8)+B0(4) landed; B1(4) may still fly.
    WAIT_VMCNT(4);
    BARRIER();

    // ---- hoist A fragments to registers (LDS read once) ----
    i32x8 af[2][4];   // [k-half][m-tile]
    #pragma unroll
    for (int h = 0; h < 2; ++h)
        #pragma unroll
        for (int t = 0; t < 4; ++t) {
            const int rA = (wm * 64 + t * 16 + lrow) * 256;
            const int g0 = ((h * 8 + quad * 2) ^ lrow) * 16;
            af[h][t] = cat8(*(const i32x4*)&As[rA + g0],
                            *(const i32x4*)&As[rA + (g0 ^ 16)]);
        }

    float rowp[4][4];   // row partials, all n
    float selfr[4][4];  // row partials, diagonal n only
    #pragma unroll
    for (int t = 0; t < 4; ++t)
        #pragma unroll
        for (int r = 0; r < 4; ++r) { rowp[t][r] = 0.f; selfr[t][r] = 0.f; }

    // Per-iteration body AFTER the vmcnt gate. Block-uniform branches only.
    auto iterBody = [&](const int n) {
        const int b = n & 1;
        BARRIER();                      // all waves: Bs[b] contents valid

        // ---- read ALL B fragments of this tile (8 x ds_read_b128) ----
        i32x8 bfr[2][2];                // [k-half][tj]
        #pragma unroll
        for (int h = 0; h < 2; ++h)
            #pragma unroll
            for (int tj = 0; tj < 2; ++tj) {
                const int rB = (wn * 32 + tj * 16 + lrow) * 256;
                const int g0 = ((h * 8 + quad * 2) ^ lrow) * 16;
                bfr[h][tj] = cat8(*(const i32x4*)&Bs[b][rB + g0],
                                  *(const i32x4*)&Bs[b][rB + (g0 ^ 16)]);
            }
        WAIT_LGKM0;                     // my reads of Bs[b] complete
        BARRIER();                      // everyone's reads done -> overwritable

        if (n < 30) {                   // stage tile n+2 into Bs[b]
            const unsigned char* src = pB + rowNbase + (size_t)(n + 2) * 64 * 8192;
            #pragma unroll
            for (int i = 0; i < 4; ++i) {
                const int lg = (lrow ^ ((i * 4 + quad) & 15)) << 4;
                async16(src + (size_t)i * 4 * 8192 + lg,
                        &Bs[b][(w * 16 + i * 4) * 256]);
            }
        }

        // ---- MFMA (regs only) ----
        f32x4 acc[4][2];
        #pragma unroll
        for (int t = 0; t < 4; ++t)
            #pragma unroll
            for (int tj = 0; tj < 2; ++tj)
                acc[t][tj] = (f32x4){0.f, 0.f, 0.f, 0.f};
        __builtin_amdgcn_s_setprio(1);
        #pragma unroll
        for (int h = 0; h < 2; ++h)
            #pragma unroll
            for (int ti = 0; ti < 4; ++ti)
                #pragma unroll
                for (int tj = 0; tj < 2; ++tj)
                    acc[ti][tj] = __builtin_amdgcn_mfma_scale_f32_16x16x128_f8f6f4(
                        af[h][ti], bfr[h][tj], acc[ti][tj],
                        0, 0, 0, 127, 0, 127);   // fp8/fp8, unit E8M0 scales
        __builtin_amdgcn_s_setprio(0);

        // ---- epilogue-accumulate: E = exp2(acc) (A prescaled by log2 e) ----
        const bool diagIter = (n >= nD0) && (n < nD0 + 4);
        float colp0 = 0.f, colp1 = 0.f;
        #pragma unroll
        for (int t = 0; t < 4; ++t)
            #pragma unroll
            for (int r = 0; r < 4; ++r) {
                float e0 = EXP2(acc[t][0][r]);
                float e1 = EXP2(acc[t][1][r]);
                rowp[t][r] += e0 + e1;
                if (diagIter) { selfr[t][r] += e0 + e1; colp0 += e0; colp1 += e1; }
            }
        if (diagIter) {   // col sums -> ap (wave-uniform branch, 4 of 32 iters)
            float q0 = colp0, q1 = colp1;
            q0 += __shfl_xor(q0, 16); q0 += __shfl_xor(q0, 32);
            q1 += __shfl_xor(q1, 16); q1 += __shfl_xor(q1, 32);
            if (lane < 16) {
                atomicAdd(&ap[n * 64 + wn * 32 + lane], q0);
                atomicAdd(&ap[n * 64 + wn * 32 + 16 + lane], q1);
            }
        }
        // no per-iter vmcnt drain: next iter's WAIT_VMCNT is the only gate
    };

    for (int n = 0; n < 31; ++n) {
        // tile n staged 2 iters ago: only the newest 4 loads (tile n+1) may
        // remain outstanding. (Diag-iter atomics only add harmless waiting.)
        WAIT_VMCNT(4);
        iterBody(n);
    }
    WAIT_VMCNT(0);       // last tile: drain everything
    iterBody(31);

    // ---- final row reductions: DPP over the 16 cols held per lane-row ----
    #pragma unroll
    for (int t = 0; t < 4; ++t)
        #pragma unroll
        for (int r = 0; r < 4; ++r) {
            float rs = rowsum16(rowp[t][r]);
            float ss = rowsum16(selfr[t][r]);
            if (lrow == 15) {
                const int idx = wm * 64 + t * 16 + quad * 4 + r;
                ls_row2[wn][idx]  = rs;
                ls_self2[wn][idx] = ss;
            }
        }
    __syncthreads();
    if (tid < 128) {
        atomicAdd(&total[tileM * 128 + tid], ls_row2[0][tid] + ls_row2[1][tid]);
    } else {
        const int t2 = tid - 128;
        atomicAdd(&selfp[tileM * 128 + t2], ls_self2[0][t2] + ls_self2[1][t2]);
    }
}

// ---------------- fallback main (round-1 kernel, fp32 staging) ---------------
__global__ __launch_bounds__(256) void infonce_main_slow(
    const float* __restrict__ feat, const float* __restrict__ feat_aug,
    float* __restrict__ total, float* __restrict__ selfp, float* __restrict__ ap)
{
    __shared__ __align__(16) unsigned short As[128][72];
    __shared__ __align__(16) unsigned short Bs[128][72];
    __shared__ float ls_row[128];
    __shared__ float ls_col[128];

    const int tid  = threadIdx.x;
    const int lane = tid & 63;
    const int w    = tid >> 6;
    const int wm   = w >> 1;
    const int wn   = w & 1;
    const int lrow = lane & 15;
    const int quad = lane >> 4;

    const int tileM = blockIdx.x & 15;
    const int tileN = blockIdx.x >> 4;
    const int v     = blockIdx.y;
    const bool diag = (tileM >> 1) == (tileN >> 1);

    if (tid < 128) ls_row[tid] = 0.0f;
    else           ls_col[tid - 128] = 0.0f;

    const float* aBase = feat     + (size_t)v * 256;
    const float* bBase = feat_aug + (size_t)v * 256;

    f32x4 acc[4][4];
    #pragma unroll
    for (int i = 0; i < 4; ++i)
        #pragma unroll
        for (int j = 0; j < 4; ++j)
            acc[i][j] = (f32x4){0.f, 0.f, 0.f, 0.f};

    const int srow = tid >> 4;
    const int scol = (tid & 15) * 4;

    for (int s = 0; s < 4; ++s) {
        const int k0 = s * 64;
        if (s) __syncthreads();
        #pragma unroll
        for (int it = 0; it < 8; ++it) {
            const int row = it * 16 + srow;
            const float4 a4 = *(const float4*)(aBase + (size_t)(tileM * 128 + row) * 8192 + k0 + scol);
            const float4 b4 = *(const float4*)(bBase + (size_t)(tileN * 128 + row) * 8192 + k0 + scol);
            uint2 wa, wb;
            wa.x = (unsigned)f2bf(a4.x) | ((unsigned)f2bf(a4.y) << 16);
            wa.y = (unsigned)f2bf(a4.z) | ((unsigned)f2bf(a4.w) << 16);
            wb.x = (unsigned)f2bf(b4.x) | ((unsigned)f2bf(b4.y) << 16);
            wb.y = (unsigned)f2bf(b4.z) | ((unsigned)f2bf(b4.w) << 16);
            *(uint2*)&As[row][scol] = wa;
            *(uint2*)&Bs[row][scol] = wb;
        }
        __syncthreads();
        #pragma unroll
        for (int kk = 0; kk < 64; kk += 32) {
            bf16x8 af[4], bfr[4];
            #pragma unroll
            for (int t = 0; t < 4; ++t) {
                af[t]  = *(const bf16x8*)&As[wm * 64 + t * 16 + lrow][kk + quad * 8];
                bfr[t] = *(const bf16x8*)&Bs[wn * 64 + t * 16 + lrow][kk + quad * 8];
            }
            #pragma unroll
            for (int ti = 0; ti < 4; ++ti)
                #pragma unroll
                for (int tj = 0; tj < 4; ++tj)
                    acc[ti][tj] = __builtin_amdgcn_mfma_f32_16x16x32_bf16(
                        af[ti], bfr[tj], acc[ti][tj], 0, 0, 0);
        }
    }

    float colp[4] = {0.f, 0.f, 0.f, 0.f};
    #pragma unroll
    for (int ti = 0; ti < 4; ++ti) {
        #pragma unroll
        for (int r = 0; r < 4; ++r) {
            float e0 = __expf(acc[ti][0][r]);
            float e1 = __expf(acc[ti][1][r]);
            float e2 = __expf(acc[ti][2][r]);
            float e3 = __expf(acc[ti][3][r]);
            colp[0] += e0; colp[1] += e1; colp[2] += e2; colp[3] += e3;
            float rp = (e0 + e1) + (e2 + e3);
            rp += __shfl_xor(rp, 1);
            rp += __shfl_xor(rp, 2);
            rp += __shfl_xor(rp, 4);
            rp += __shfl_xor(rp, 8);
            if (lrow == 0)
                atomicAdd(&ls_row[wm * 64 + ti * 16 + quad * 4 + r], rp);
        }
    }
    if (diag) {
        #pragma unroll
        for (int tj = 0; tj < 4; ++tj) {
            float q = colp[tj];
            q += __shfl_xor(q, 16);
            q += __shfl_xor(q, 32);
            if (lane < 16)
                atomicAdd(&ls_col[wn * 64 + tj * 16 + lane], q);
        }
    }
    __syncthreads();
    if (tid < 128) {
        const float rs = ls_row[tid];
        const int rowg = tileM * 128 + tid;
        atomicAdd(&total[rowg], rs);
        if (diag) atomicAdd(&selfp[rowg], rs);
    } else if (diag) {
        const int t2 = tid - 128;
        atomicAdd(&ap[tileN * 128 + t2], ls_col[t2]);
    }
}

__global__ __launch_bounds__(256) void infonce_finalize(
    const float* __restrict__ total, const float* __restrict__ selfp,
    const float* __restrict__ ap, float* __restrict__ out)
{
    __shared__ float red[4];
    const int tid = threadIdx.x;
    float s = 0.f;
    for (int e = tid; e < 2048; e += 256) {
        const float an = total[e] - selfp[e];
        s += logf(an / ap[e]);
    }
    #pragma unroll
    for (int m = 32; m >= 1; m >>= 1) s += __shfl_xor(s, m);
    if ((tid & 63) == 0) red[tid >> 6] = s;
    __syncthreads();
    if (tid == 0) out[0] = (red[0] + red[1] + red[2] + red[3]) * (1.0f / 256.0f);
}

extern "C" void kernel_launch(void* const* d_in, const int* in_sizes, int n_in,
                              void* d_out, int out_size, void* d_ws, size_t ws_size,
                              hipStream_t stream) {
    const float* feat     = (const float*)d_in[0];
    const float* feat_aug = (const float*)d_in[1];
    float* total = (float*)d_ws;
    float* selfp = total + 2048;
    float* ap    = selfp + 2048;

    const size_t packBytes = (size_t)2048 * 8192;                  // per tensor, fp8
    const size_t need = 32768 + 2 * packBytes;
    if (ws_size >= need) {
        unsigned char* pA = (unsigned char*)d_ws + 32768;
        unsigned char* pB = pA + packBytes;
        infonce_repack_fp8<<<dim3(2048, 2), 256, 0, stream>>>(feat, feat_aug, pA, pB, total);
        infonce_main_nl<<<dim3(16, 32), 256, 0, stream>>>(pA, pB, total, selfp, ap);
    } else {
        (void)hipMemsetAsync(d_ws, 0, 3 * 2048 * sizeof(float), stream);
        infonce_main_slow<<<dim3(256, 32), 256, 0, stream>>>(feat, feat_aug, total, selfp, ap);
    }
    infonce_finalize<<<1, 256, 0, stream>>>(total, selfp, ap, (float*)d_out);
}